// Round 1
// baseline (1198.605 us; speedup 1.0000x reference)
//
#include <hip/hip_runtime.h>
#include <hip/hip_bf16.h>

#define N_USERS    50000
#define N_ENTITIES 100000
#define N_FACTORS  8
#define EMB        64
#define N_EDGES    2000000
#define NNZ        2000000
#define SLOPE      0.2f

// ---------------------------------------------------------------------------
// Kernel A: KG aggregate scatter.  thread = (edge, dim).  64 lanes of one
// wave handle the 64 dims of one edge -> fully coalesced gather of
// entity_emb[tail] and weight[type-1]; atomic scatter into sums[head].
// ---------------------------------------------------------------------------
__global__ void kg_scatter(const int* __restrict__ head,
                           const int* __restrict__ tail,
                           const int* __restrict__ etype,
                           const float* __restrict__ entity_emb,
                           const float* __restrict__ weight,
                           float* __restrict__ sums,
                           float* __restrict__ cnt) {
    int gid = blockIdx.x * blockDim.x + threadIdx.x;
    int e = gid >> 6;
    int d = threadIdx.x & 63;
    if (e >= N_EDGES) return;
    int h = head[e];
    int t = tail[e];
    int w = etype[e] - 1;
    float v = entity_emb[t * EMB + d] * weight[w * EMB + d];
    unsafeAtomicAdd(&sums[h * EMB + d], v);
    if (d == 0) unsafeAtomicAdd(&cnt[h], 1.0f);
}

// ---------------------------------------------------------------------------
// Kernel B: user aggregate scatter (COO spmm): vals * entity_emb[col] -> row
// ---------------------------------------------------------------------------
__global__ void user_scatter(const int* __restrict__ rows,
                             const int* __restrict__ cols,
                             const float* __restrict__ vals,
                             const float* __restrict__ entity_emb,
                             float* __restrict__ user_sums) {
    int gid = blockIdx.x * blockDim.x + threadIdx.x;
    int e = gid >> 6;
    int d = threadIdx.x & 63;
    if (e >= NNZ) return;
    int r = rows[e];
    int c = cols[e];
    float v = vals[e] * entity_emb[c * EMB + d];
    unsafeAtomicAdd(&user_sums[r * EMB + d], v);
}

// ---------------------------------------------------------------------------
// Kernel C: all the tiny dense math, one wave.
// Produces: latent_new [8,64] (output 2), P [64,8], c [8]  (for kernel D)
//   lat1 = latent_emb @ W1^T + b1         [8,64]
//   lat2 = latent_emb @ W2^T + b2         [8,64]
//   wl2  = weight     @ W2^T + b2         [16,64]
//   P[k,f] = sum_d W1[d,k] * lat1[f,d];   c[f] = dot(b1, lat1[f])
//   srp[f,r] = dot(lat2[f], wl2[r])
//   latent_new = softmax_r(leaky(srp @ Wwa^T + bwa)) @ weight
// ---------------------------------------------------------------------------
__global__ void small_dense(const float* __restrict__ latent_emb,
                            const float* __restrict__ weight,
                            const float* __restrict__ W_weight_att,
                            const float* __restrict__ b_weight_att,
                            const float* __restrict__ W1,
                            const float* __restrict__ b1,
                            const float* __restrict__ W2,
                            const float* __restrict__ b2,
                            float* __restrict__ P_out,
                            float* __restrict__ c_out,
                            float* __restrict__ latent_new_out) {
    __shared__ float lat1[8 * 64];
    __shared__ float lat2[8 * 64];
    __shared__ float wl2[16 * 64];
    __shared__ float srp[8 * 16];
    __shared__ float soft[8 * 16];
    int l = threadIdx.x;  // 0..63

    for (int f = 0; f < 8; ++f) {
        float a1 = b1[l], a2 = b2[l];
        for (int k = 0; k < 64; ++k) {
            float le = latent_emb[f * 64 + k];
            a1 += le * W1[l * 64 + k];
            a2 += le * W2[l * 64 + k];
        }
        lat1[f * 64 + l] = a1;
        lat2[f * 64 + l] = a2;
    }
    for (int r = 0; r < 16; ++r) {
        float a = b2[l];
        for (int k = 0; k < 64; ++k) a += weight[r * 64 + k] * W2[l * 64 + k];
        wl2[r * 64 + l] = a;
    }
    __syncthreads();

    // P row l, and c
    for (int f = 0; f < 8; ++f) {
        float p = 0.f;
        for (int d = 0; d < 64; ++d) p += W1[d * 64 + l] * lat1[f * 64 + d];
        P_out[l * 8 + f] = p;
    }
    if (l < 8) {
        float cc = 0.f;
        for (int d = 0; d < 64; ++d) cc += b1[d] * lat1[l * 64 + d];
        c_out[l] = cc;
    }
    // score_rp (128 entries, 2 per lane)
    for (int idx = l; idx < 128; idx += 64) {
        int f = idx >> 4, r = idx & 15;
        float a = 0.f;
        for (int d = 0; d < 64; ++d) a += lat2[f * 64 + d] * wl2[r * 64 + d];
        srp[idx] = a;
    }
    __syncthreads();

    if (l < 8) {
        int f = l;
        float att[16];
        float mx = -1e30f;
        for (int i = 0; i < 16; ++i) {
            float a = b_weight_att[i];
            for (int j = 0; j < 16; ++j) a += srp[f * 16 + j] * W_weight_att[i * 16 + j];
            a = a > 0.f ? a : SLOPE * a;
            att[i] = a;
            mx = fmaxf(mx, a);
        }
        float s = 0.f;
        for (int i = 0; i < 16; ++i) {
            att[i] = expf(att[i] - mx);
            s += att[i];
        }
        float inv = 1.f / s;
        for (int i = 0; i < 16; ++i) soft[f * 16 + i] = att[i] * inv;
    }
    __syncthreads();

    for (int f = 0; f < 8; ++f) {
        float a = 0.f;
        for (int r = 0; r < 16; ++r) a += soft[f * 16 + r] * weight[r * 64 + l];
        latent_new_out[f * 64 + l] = a;
    }
}

// ---------------------------------------------------------------------------
// Kernel D: per-user attention + gating.  One wave per user.
//   score_ = user_emb[u] @ P + c            (butterfly reduce over 64 lanes)
//   score  = softmax(leaky(score_ @ Wua^T + bua))
//   user_out[u] *= 1 + score @ latent_new
// ---------------------------------------------------------------------------
__global__ void user_finalize(const float* __restrict__ user_emb,
                              const float* __restrict__ P,
                              const float* __restrict__ c,
                              const float* __restrict__ W_user_att,
                              const float* __restrict__ b_user_att,
                              const float* __restrict__ latent_new,
                              float* __restrict__ user_out) {
    int gid = blockIdx.x * blockDim.x + threadIdx.x;
    int u = gid >> 6;
    int lane = threadIdx.x & 63;
    if (u >= N_USERS) return;

    float ue = user_emb[u * 64 + lane];
    float s[8];
#pragma unroll
    for (int f = 0; f < 8; ++f) s[f] = ue * P[lane * 8 + f];
#pragma unroll
    for (int off = 32; off; off >>= 1) {
#pragma unroll
        for (int f = 0; f < 8; ++f) s[f] += __shfl_xor(s[f], off, 64);
    }
#pragma unroll
    for (int f = 0; f < 8; ++f) s[f] += c[f];

    float att[8];
    float mx = -1e30f;
#pragma unroll
    for (int i = 0; i < 8; ++i) {
        float a = b_user_att[i];
#pragma unroll
        for (int j = 0; j < 8; ++j) a += s[j] * W_user_att[i * 8 + j];
        a = a > 0.f ? a : SLOPE * a;
        att[i] = a;
        mx = fmaxf(mx, a);
    }
    float sum = 0.f;
#pragma unroll
    for (int i = 0; i < 8; ++i) {
        att[i] = expf(att[i] - mx);
        sum += att[i];
    }
    float inv = 1.f / sum;
    float g = 0.f;
#pragma unroll
    for (int f = 0; f < 8; ++f) g += att[f] * inv * latent_new[f * 64 + lane];

    float ua = user_out[u * 64 + lane];
    user_out[u * 64 + lane] = ua * (1.f + g);
}

// ---------------------------------------------------------------------------
// Kernel E: entity mean = sums / max(cnt,1)
// ---------------------------------------------------------------------------
__global__ void entity_div(float* __restrict__ ent, const float* __restrict__ cnt) {
    int gid = blockIdx.x * blockDim.x + threadIdx.x;
    if (gid >= N_ENTITIES * EMB) return;
    float c = cnt[gid >> 6];
    ent[gid] = ent[gid] / fmaxf(c, 1.0f);
}

extern "C" void kernel_launch(void* const* d_in, const int* in_sizes, int n_in,
                              void* d_out, int out_size, void* d_ws, size_t ws_size,
                              hipStream_t stream) {
    const float* entity_emb   = (const float*)d_in[0];
    const float* user_emb     = (const float*)d_in[1];
    const float* latent_emb   = (const float*)d_in[2];
    const int*   edge_index   = (const int*)d_in[3];   // [2, E]
    const int*   edge_type    = (const int*)d_in[4];
    const int*   irows        = (const int*)d_in[5];
    const int*   icols        = (const int*)d_in[6];
    const float* ivals        = (const float*)d_in[7];
    const float* weight       = (const float*)d_in[8];
    // d_in[9] entity_cate_set: unused by reference outputs
    const float* W_user_att   = (const float*)d_in[10];
    const float* b_user_att   = (const float*)d_in[11];
    const float* W_weight_att = (const float*)d_in[12];
    const float* b_weight_att = (const float*)d_in[13];
    const float* W1           = (const float*)d_in[14];
    const float* b1           = (const float*)d_in[15];
    const float* W2           = (const float*)d_in[16];
    const float* b2           = (const float*)d_in[17];

    float* out      = (float*)d_out;
    float* ent_out  = out;                                    // 6,400,000
    float* user_out = out + (size_t)N_ENTITIES * EMB;         // 3,200,000
    float* lat_out  = user_out + (size_t)N_USERS * EMB;       // 512

    float* ws   = (float*)d_ws;
    float* cnt  = ws;               // 100000
    float* Pbuf = ws + N_ENTITIES;  // 512
    float* cbuf = Pbuf + 64 * 8;    // 8

    // zero accumulators (d_out / d_ws are poisoned 0xAA before every call)
    hipMemsetAsync(ent_out, 0, (size_t)(N_ENTITIES + N_USERS) * EMB * sizeof(float), stream);
    hipMemsetAsync(cnt, 0, N_ENTITIES * sizeof(float), stream);

    const int* head = edge_index;
    const int* tail = edge_index + N_EDGES;

    int blocks_edges = (N_EDGES * 64) / 256;  // 500000
    kg_scatter<<<blocks_edges, 256, 0, stream>>>(head, tail, edge_type, entity_emb,
                                                 weight, ent_out, cnt);
    user_scatter<<<blocks_edges, 256, 0, stream>>>(irows, icols, ivals, entity_emb,
                                                   user_out);
    small_dense<<<1, 64, 0, stream>>>(latent_emb, weight, W_weight_att, b_weight_att,
                                      W1, b1, W2, b2, Pbuf, cbuf, lat_out);
    user_finalize<<<(N_USERS * 64) / 256, 256, 0, stream>>>(user_emb, Pbuf, cbuf,
                                                            W_user_att, b_user_att,
                                                            lat_out, user_out);
    entity_div<<<(N_ENTITIES * EMB) / 256, 256, 0, stream>>>(ent_out, cnt);
}

// Round 2
// 940.944 us; speedup vs baseline: 1.2738x; 1.2738x over previous
//
#include <hip/hip_runtime.h>
#include <hip/hip_bf16.h>

#define N_USERS    50000
#define N_ENTITIES 100000
#define N_FACTORS  8
#define EMB        64
#define N_EDGES    2000000
#define NNZ        2000000
#define SLOPE      0.2f

// ============================================================================
// Sorted-segment path: counting sort by destination row, then wave-per-row
// segment sum with no f32 atomics.
// ============================================================================

// --- histogram: counts[key[e]]++ ------------------------------------------
__global__ void hist_kernel(const int* __restrict__ key, int* __restrict__ counts,
                            int n, int sub) {
    int e = blockIdx.x * blockDim.x + threadIdx.x;
    if (e >= n) return;
    atomicAdd(&counts[key[e] - sub], 1);
}

// --- two-level exclusive scan ---------------------------------------------
__global__ void scan_partial(int* __restrict__ data, int* __restrict__ bsums, int n) {
    __shared__ int tmp[256];
    int tid = threadIdx.x;
    int gid = blockIdx.x * 256 + tid;
    int v = (gid < n) ? data[gid] : 0;
    tmp[tid] = v;
    __syncthreads();
    for (int off = 1; off < 256; off <<= 1) {
        int t = (tid >= off) ? tmp[tid - off] : 0;
        __syncthreads();
        tmp[tid] += t;
        __syncthreads();
    }
    if (gid < n) data[gid] = tmp[tid] - v;   // exclusive
    if (tid == 255) bsums[blockIdx.x] = tmp[255];
}

__global__ void scan_bsums(int* __restrict__ bsums, int nb, int* __restrict__ total_out) {
    __shared__ int tmp[512];
    int tid = threadIdx.x;
    int v = (tid < nb) ? bsums[tid] : 0;
    tmp[tid] = v;
    __syncthreads();
    for (int off = 1; off < 512; off <<= 1) {
        int t = (tid >= off) ? tmp[tid - off] : 0;
        __syncthreads();
        tmp[tid] += t;
        __syncthreads();
    }
    if (tid < nb) bsums[tid] = tmp[tid] - v;  // exclusive
    if (tid == 511) *total_out = tmp[511];
}

__global__ void scan_add(int* __restrict__ offs, int* __restrict__ cursor,
                         const int* __restrict__ bsums, int n) {
    int gid = blockIdx.x * 256 + threadIdx.x;
    if (gid < n) {
        int o = offs[gid] + bsums[blockIdx.x];
        offs[gid] = o;
        cursor[gid] = o;
    }
}

// --- bin KG edges: pack tail | (type-1)<<17 into sorted order --------------
__global__ void kg_bin(const int* __restrict__ head, const int* __restrict__ tail,
                       const int* __restrict__ etype, int* __restrict__ cursor,
                       int* __restrict__ tt, int n) {
    int e = blockIdx.x * blockDim.x + threadIdx.x;
    if (e >= n) return;
    int pos = atomicAdd(&cursor[head[e]], 1);
    tt[pos] = tail[e] | ((etype[e] - 1) << 17);
}

__global__ void user_bin(const int* __restrict__ rows, const int* __restrict__ cols,
                         const float* __restrict__ vals, int* __restrict__ cursor,
                         int* __restrict__ scol, float* __restrict__ sval, int n) {
    int e = blockIdx.x * blockDim.x + threadIdx.x;
    if (e >= n) return;
    int pos = atomicAdd(&cursor[rows[e]], 1);
    scol[pos] = cols[e];
    sval[pos] = vals[e];
}

// --- segment sums: one wave per output row ---------------------------------
__global__ void kg_seg(const int* __restrict__ tt, const int* __restrict__ offs,
                       const float* __restrict__ entity_emb,
                       const float* __restrict__ weight,
                       float* __restrict__ out) {
    int wid = (blockIdx.x * blockDim.x + threadIdx.x) >> 6;
    int d = threadIdx.x & 63;
    if (wid >= N_ENTITIES) return;
    int start = offs[wid], end = offs[wid + 1];
    float acc = 0.f;
    int i = start;
    for (; i + 1 < end; i += 2) {
        int v0 = tt[i], v1 = tt[i + 1];
        float a = entity_emb[(v0 & 0x1FFFF) * EMB + d] * weight[(v0 >> 17) * EMB + d];
        float b = entity_emb[(v1 & 0x1FFFF) * EMB + d] * weight[(v1 >> 17) * EMB + d];
        acc += a + b;
    }
    if (i < end) {
        int v = tt[i];
        acc += entity_emb[(v & 0x1FFFF) * EMB + d] * weight[(v >> 17) * EMB + d];
    }
    float c = (float)(end - start);
    out[wid * EMB + d] = acc / fmaxf(c, 1.f);
}

__global__ void user_seg(const int* __restrict__ scol, const float* __restrict__ sval,
                         const int* __restrict__ offs,
                         const float* __restrict__ entity_emb,
                         float* __restrict__ out) {
    int wid = (blockIdx.x * blockDim.x + threadIdx.x) >> 6;
    int d = threadIdx.x & 63;
    if (wid >= N_USERS) return;
    int start = offs[wid], end = offs[wid + 1];
    float acc = 0.f;
    int i = start;
    for (; i + 1 < end; i += 2) {
        float a = sval[i] * entity_emb[scol[i] * EMB + d];
        float b = sval[i + 1] * entity_emb[scol[i + 1] * EMB + d];
        acc += a + b;
    }
    if (i < end) acc += sval[i] * entity_emb[scol[i] * EMB + d];
    out[wid * EMB + d] = acc;
}

// ============================================================================
// Fallback atomic path (verified last round) — used only if ws too small
// ============================================================================
__global__ void kg_scatter(const int* __restrict__ head, const int* __restrict__ tail,
                           const int* __restrict__ etype,
                           const float* __restrict__ entity_emb,
                           const float* __restrict__ weight,
                           float* __restrict__ sums, float* __restrict__ cnt) {
    int gid = blockIdx.x * blockDim.x + threadIdx.x;
    int e = gid >> 6;
    int d = threadIdx.x & 63;
    if (e >= N_EDGES) return;
    int h = head[e], t = tail[e], w = etype[e] - 1;
    float v = entity_emb[t * EMB + d] * weight[w * EMB + d];
    unsafeAtomicAdd(&sums[h * EMB + d], v);
    if (d == 0) unsafeAtomicAdd(&cnt[h], 1.0f);
}

__global__ void user_scatter(const int* __restrict__ rows, const int* __restrict__ cols,
                             const float* __restrict__ vals,
                             const float* __restrict__ entity_emb,
                             float* __restrict__ user_sums) {
    int gid = blockIdx.x * blockDim.x + threadIdx.x;
    int e = gid >> 6;
    int d = threadIdx.x & 63;
    if (e >= NNZ) return;
    float v = vals[e] * entity_emb[cols[e] * EMB + d];
    unsafeAtomicAdd(&user_sums[rows[e] * EMB + d], v);
}

__global__ void entity_div(float* __restrict__ ent, const float* __restrict__ cnt) {
    int gid = blockIdx.x * blockDim.x + threadIdx.x;
    if (gid >= N_ENTITIES * EMB) return;
    float c = cnt[gid >> 6];
    ent[gid] = ent[gid] / fmaxf(c, 1.0f);
}

// ============================================================================
// Small dense math (one wave): latent_new, P = W1^T·lat1^T, c = b1·lat1^T
// ============================================================================
__global__ void small_dense(const float* __restrict__ latent_emb,
                            const float* __restrict__ weight,
                            const float* __restrict__ W_weight_att,
                            const float* __restrict__ b_weight_att,
                            const float* __restrict__ W1,
                            const float* __restrict__ b1,
                            const float* __restrict__ W2,
                            const float* __restrict__ b2,
                            float* __restrict__ P_out,
                            float* __restrict__ c_out,
                            float* __restrict__ latent_new_out) {
    __shared__ float lat1[8 * 64];
    __shared__ float lat2[8 * 64];
    __shared__ float wl2[16 * 64];
    __shared__ float srp[8 * 16];
    __shared__ float soft[8 * 16];
    int l = threadIdx.x;  // 0..63

    for (int f = 0; f < 8; ++f) {
        float a1 = b1[l], a2 = b2[l];
        for (int k = 0; k < 64; ++k) {
            float le = latent_emb[f * 64 + k];
            a1 += le * W1[l * 64 + k];
            a2 += le * W2[l * 64 + k];
        }
        lat1[f * 64 + l] = a1;
        lat2[f * 64 + l] = a2;
    }
    for (int r = 0; r < 16; ++r) {
        float a = b2[l];
        for (int k = 0; k < 64; ++k) a += weight[r * 64 + k] * W2[l * 64 + k];
        wl2[r * 64 + l] = a;
    }
    __syncthreads();

    for (int f = 0; f < 8; ++f) {
        float p = 0.f;
        for (int d = 0; d < 64; ++d) p += W1[d * 64 + l] * lat1[f * 64 + d];
        P_out[l * 8 + f] = p;
    }
    if (l < 8) {
        float cc = 0.f;
        for (int d = 0; d < 64; ++d) cc += b1[d] * lat1[l * 64 + d];
        c_out[l] = cc;
    }
    for (int idx = l; idx < 128; idx += 64) {
        int f = idx >> 4, r = idx & 15;
        float a = 0.f;
        for (int d = 0; d < 64; ++d) a += lat2[f * 64 + d] * wl2[r * 64 + d];
        srp[idx] = a;
    }
    __syncthreads();

    if (l < 8) {
        int f = l;
        float att[16];
        float mx = -1e30f;
        for (int i = 0; i < 16; ++i) {
            float a = b_weight_att[i];
            for (int j = 0; j < 16; ++j) a += srp[f * 16 + j] * W_weight_att[i * 16 + j];
            a = a > 0.f ? a : SLOPE * a;
            att[i] = a;
            mx = fmaxf(mx, a);
        }
        float s = 0.f;
        for (int i = 0; i < 16; ++i) { att[i] = expf(att[i] - mx); s += att[i]; }
        float inv = 1.f / s;
        for (int i = 0; i < 16; ++i) soft[f * 16 + i] = att[i] * inv;
    }
    __syncthreads();

    for (int f = 0; f < 8; ++f) {
        float a = 0.f;
        for (int r = 0; r < 16; ++r) a += soft[f * 16 + r] * weight[r * 64 + l];
        latent_new_out[f * 64 + l] = a;
    }
}

// ============================================================================
// Per-user attention + gating: one wave per user
// ============================================================================
__global__ void user_finalize(const float* __restrict__ user_emb,
                              const float* __restrict__ P,
                              const float* __restrict__ c,
                              const float* __restrict__ W_user_att,
                              const float* __restrict__ b_user_att,
                              const float* __restrict__ latent_new,
                              float* __restrict__ user_out) {
    int gid = blockIdx.x * blockDim.x + threadIdx.x;
    int u = gid >> 6;
    int lane = threadIdx.x & 63;
    if (u >= N_USERS) return;

    float ue = user_emb[u * 64 + lane];
    float s[8];
#pragma unroll
    for (int f = 0; f < 8; ++f) s[f] = ue * P[lane * 8 + f];
#pragma unroll
    for (int off = 32; off; off >>= 1) {
#pragma unroll
        for (int f = 0; f < 8; ++f) s[f] += __shfl_xor(s[f], off, 64);
    }
#pragma unroll
    for (int f = 0; f < 8; ++f) s[f] += c[f];

    float att[8];
    float mx = -1e30f;
#pragma unroll
    for (int i = 0; i < 8; ++i) {
        float a = b_user_att[i];
#pragma unroll
        for (int j = 0; j < 8; ++j) a += s[j] * W_user_att[i * 8 + j];
        a = a > 0.f ? a : SLOPE * a;
        att[i] = a;
        mx = fmaxf(mx, a);
    }
    float sum = 0.f;
#pragma unroll
    for (int i = 0; i < 8; ++i) { att[i] = expf(att[i] - mx); sum += att[i]; }
    float inv = 1.f / sum;
    float g = 0.f;
#pragma unroll
    for (int f = 0; f < 8; ++f) g += att[f] * inv * latent_new[f * 64 + lane];

    float ua = user_out[u * 64 + lane];
    user_out[u * 64 + lane] = ua * (1.f + g);
}

extern "C" void kernel_launch(void* const* d_in, const int* in_sizes, int n_in,
                              void* d_out, int out_size, void* d_ws, size_t ws_size,
                              hipStream_t stream) {
    const float* entity_emb   = (const float*)d_in[0];
    const float* user_emb     = (const float*)d_in[1];
    const float* latent_emb   = (const float*)d_in[2];
    const int*   edge_index   = (const int*)d_in[3];   // [2, E]
    const int*   edge_type    = (const int*)d_in[4];
    const int*   irows        = (const int*)d_in[5];
    const int*   icols        = (const int*)d_in[6];
    const float* ivals        = (const float*)d_in[7];
    const float* weight       = (const float*)d_in[8];
    const float* W_user_att   = (const float*)d_in[10];
    const float* b_user_att   = (const float*)d_in[11];
    const float* W_weight_att = (const float*)d_in[12];
    const float* b_weight_att = (const float*)d_in[13];
    const float* W1           = (const float*)d_in[14];
    const float* b1           = (const float*)d_in[15];
    const float* W2           = (const float*)d_in[16];
    const float* b2           = (const float*)d_in[17];

    float* out      = (float*)d_out;
    float* ent_out  = out;
    float* user_out = out + (size_t)N_ENTITIES * EMB;
    float* lat_out  = user_out + (size_t)N_USERS * EMB;

    const int* head = edge_index;
    const int* tail = edge_index + N_EDGES;

    // ---- workspace layout (ints unless noted) ----
    int* ws_i = (int*)d_ws;
    int*   ecnt   = ws_i;                      // 100001 (counts -> offsets, [N]=total)
    int*   ecur   = ecnt + (N_ENTITIES + 1);   // 100000
    int*   ett    = ecur + N_ENTITIES;         // 2,000,000 packed tail|type
    int*   ucnt   = ett + N_EDGES;             // 50001
    int*   ucur   = ucnt + (N_USERS + 1);      // 50000
    int*   ucol   = ucur + N_USERS;            // 2,000,000
    float* uvalS  = (float*)(ucol + NNZ);      // 2,000,000
    int*   bsumA  = (int*)(uvalS + NNZ);       // 512
    int*   bsumB  = bsumA + 512;               // 512
    float* Pbuf   = (float*)(bsumB + 512);     // 512
    float* cbuf   = Pbuf + 64 * 8;             // 8
    size_t need_bytes = (size_t)((N_ENTITIES + 1) + N_ENTITIES + N_EDGES +
                                 (N_USERS + 1) + N_USERS + NNZ + NNZ +
                                 512 + 512 + 512 + 8) * 4;

    const int EB = (N_EDGES + 255) / 256;      // 1-thread-per-edge grids

    if (ws_size >= need_bytes) {
        // ---------- sorted-segment path ----------
        hipMemsetAsync(ecnt, 0, (size_t)(N_ENTITIES + 1) * sizeof(int), stream);
        hipMemsetAsync(ucnt, 0, (size_t)(N_USERS + 1) * sizeof(int), stream);

        hist_kernel<<<EB, 256, 0, stream>>>(head, ecnt, N_EDGES, 0);
        hist_kernel<<<EB, 256, 0, stream>>>(irows, ucnt, NNZ, 0);

        int nbA = (N_ENTITIES + 255) / 256;    // 391
        int nbB = (N_USERS + 255) / 256;       // 196
        scan_partial<<<nbA, 256, 0, stream>>>(ecnt, bsumA, N_ENTITIES);
        scan_partial<<<nbB, 256, 0, stream>>>(ucnt, bsumB, N_USERS);
        scan_bsums<<<1, 512, 0, stream>>>(bsumA, nbA, ecnt + N_ENTITIES);
        scan_bsums<<<1, 512, 0, stream>>>(bsumB, nbB, ucnt + N_USERS);
        scan_add<<<nbA, 256, 0, stream>>>(ecnt, ecur, bsumA, N_ENTITIES);
        scan_add<<<nbB, 256, 0, stream>>>(ucnt, ucur, bsumB, N_USERS);

        kg_bin<<<EB, 256, 0, stream>>>(head, tail, edge_type, ecur, ett, N_EDGES);
        user_bin<<<EB, 256, 0, stream>>>(irows, icols, ivals, ucur, ucol, uvalS, NNZ);

        kg_seg<<<(N_ENTITIES * 64) / 256, 256, 0, stream>>>(ett, ecnt, entity_emb,
                                                            weight, ent_out);
        user_seg<<<(N_USERS * 64) / 256, 256, 0, stream>>>(ucol, uvalS, ucnt,
                                                           entity_emb, user_out);

        small_dense<<<1, 64, 0, stream>>>(latent_emb, weight, W_weight_att,
                                          b_weight_att, W1, b1, W2, b2,
                                          Pbuf, cbuf, lat_out);
        user_finalize<<<(N_USERS * 64) / 256, 256, 0, stream>>>(user_emb, Pbuf, cbuf,
                                                                W_user_att, b_user_att,
                                                                lat_out, user_out);
    } else {
        // ---------- fallback atomic path ----------
        float* cnt   = (float*)d_ws;
        float* Pbuf2 = cnt + N_ENTITIES;
        float* cbuf2 = Pbuf2 + 64 * 8;
        hipMemsetAsync(ent_out, 0,
                       (size_t)(N_ENTITIES + N_USERS) * EMB * sizeof(float), stream);
        hipMemsetAsync(cnt, 0, N_ENTITIES * sizeof(float), stream);
        int blocks_edges = (N_EDGES * 64) / 256;
        kg_scatter<<<blocks_edges, 256, 0, stream>>>(head, tail, edge_type, entity_emb,
                                                     weight, ent_out, cnt);
        user_scatter<<<blocks_edges, 256, 0, stream>>>(irows, icols, ivals, entity_emb,
                                                       user_out);
        small_dense<<<1, 64, 0, stream>>>(latent_emb, weight, W_weight_att,
                                          b_weight_att, W1, b1, W2, b2,
                                          Pbuf2, cbuf2, lat_out);
        user_finalize<<<(N_USERS * 64) / 256, 256, 0, stream>>>(user_emb, Pbuf2, cbuf2,
                                                                W_user_att, b_user_att,
                                                                lat_out, user_out);
        entity_div<<<(N_ENTITIES * EMB) / 256, 256, 0, stream>>>(ent_out, cnt);
    }
}